// Round 9
// baseline (370.257 us; speedup 1.0000x reference)
//
#include <hip/hip_runtime.h>
#include <hip/hip_bf16.h>
#include <math.h>

#define N_NODES 20000
#define N_EDGES 320000
#define DIM 512
#define HEADS 4
#define DHEAD 128
#define NEG_SLOPE 0.2f
#define BM 64
#define BN 64
#define BK 64

typedef __attribute__((ext_vector_type(8))) short short8;
typedef __attribute__((ext_vector_type(8))) __bf16 bf16x8;
typedef __attribute__((ext_vector_type(4))) float f32x4;

static __device__ __forceinline__ unsigned short f32_to_bf16(float f) {
    union { float f; unsigned u; } v; v.f = f;
    unsigned u = v.u;
    u += 0x7FFFu + ((u >> 16) & 1u);   // round-to-nearest-even
    return (unsigned short)(u >> 16);
}
static __device__ __forceinline__ float bf16_to_f32(unsigned short s) {
    union { unsigned u; float f; } v; v.u = ((unsigned)s) << 16;
    return v.f;
}
static __device__ __forceinline__ float bits_f32(unsigned u) {
    union { unsigned u; float f; } v; v.u = u;
    return v.f;
}

static __device__ __forceinline__ void gl_lds16(const unsigned short* g, unsigned short* l) {
    __builtin_amdgcn_global_load_lds(
        (const __attribute__((address_space(1))) unsigned int*)g,
        (__attribute__((address_space(3))) unsigned int*)l, 16, 0, 0);
}

// ---------------- histogram (generic over key array) ----------------
__global__ void k_hist(const int* __restrict__ key, int* __restrict__ counts) {
    int e = blockIdx.x * blockDim.x + threadIdx.x;
    if (e >= N_EDGES) return;
    atomicAdd(&counts[key[e]], 1);
}

__global__ void k_scan(const int* __restrict__ counts, int* __restrict__ offsets,
                       int* __restrict__ cursor) {
    __shared__ int lds[1024];
    int t = threadIdx.x;
    const int CH = (N_NODES + 1023) / 1024;   // 20
    int base = t * CH;
    int sum = 0;
    for (int j = 0; j < CH; j++) {
        int i = base + j;
        if (i < N_NODES) sum += counts[i];
    }
    lds[t] = sum;
    __syncthreads();
    for (int off = 1; off < 1024; off <<= 1) {
        int other = (t >= off) ? lds[t - off] : 0;
        __syncthreads();
        lds[t] += other;
        __syncthreads();
    }
    int excl = lds[t] - sum;
    int run = excl;
    for (int j = 0; j < CH; j++) {
        int i = base + j;
        if (i < N_NODES) {
            offsets[i] = run;
            cursor[i] = run;
            run += counts[i];
        }
    }
    if (t == 0) offsets[N_NODES] = N_EDGES;
}

// scatter edges into src-sorted order: sdst[p], ssrc[p] for p ascending in src
__global__ void k_scatter(const int* __restrict__ src, const int* __restrict__ dst,
                          int* __restrict__ scursor, int* __restrict__ sdst,
                          int* __restrict__ ssrc) {
    int e = blockIdx.x * blockDim.x + threadIdx.x;
    if (e >= N_EDGES) return;
    int s = src[e];
    int p = atomicAdd(&scursor[s], 1);
    sdst[p] = dst[e];
    ssrc[p] = s;
}

// fill dst-CSR scanning the src-sorted list -> buckets ascending by src (statistically)
__global__ void k_fill(const int* __restrict__ sdst, const int* __restrict__ ssrc,
                       int* __restrict__ cursor, int* __restrict__ csr_src) {
    int p = blockIdx.x * blockDim.x + threadIdx.x;
    if (p >= N_EDGES) return;
    int d = sdst[p];
    int q = atomicAdd(&cursor[d], 1);
    csr_src[q] = ssrc[p];
}

// ---------------- cast x -> bf16 row-major ----------------
__global__ void k_cast(const float* __restrict__ in, unsigned short* __restrict__ out, int n8) {
    int i = blockIdx.x * blockDim.x + threadIdx.x;
    if (i >= n8) return;
    const float4* p = reinterpret_cast<const float4*>(in) + (size_t)i * 2;
    float4 a = p[0], b = p[1];
    short8 o;
    o[0] = (short)f32_to_bf16(a.x); o[1] = (short)f32_to_bf16(a.y);
    o[2] = (short)f32_to_bf16(a.z); o[3] = (short)f32_to_bf16(a.w);
    o[4] = (short)f32_to_bf16(b.x); o[5] = (short)f32_to_bf16(b.y);
    o[6] = (short)f32_to_bf16(b.z); o[7] = (short)f32_to_bf16(b.w);
    *reinterpret_cast<short8*>(out + (size_t)i * 8) = o;
}

// W: (H, D, DH) f32 -> Bt: [col][k] bf16, col=h*128+f, k over D
__global__ void k_transW(const float* __restrict__ W, unsigned short* __restrict__ Bt) {
    int id = blockIdx.x * blockDim.x + threadIdx.x;
    if (id >= 512 * 64) return;
    int col = id >> 6;
    int kg = id & 63;
    int h = col >> 7;
    int f = col & 127;
    short8 o;
#pragma unroll
    for (int j = 0; j < 8; j++) {
        int k = kg * 8 + j;
        o[j] = (short)f32_to_bf16(W[(size_t)h * DIM * DHEAD + (size_t)k * DHEAD + f]);
    }
    *reinterpret_cast<short8*>(Bt + (size_t)col * DIM + kg * 8) = o;
}

// ---------------- w-tilde: wt[v][k] = sum_f W[h][k][f] * a[h][sd*128+f], v=h*2+sd ----------------
__global__ void k_wtilde(const float* __restrict__ W, const float* __restrict__ a,
                         float* __restrict__ wt) {
    int id = blockIdx.x * blockDim.x + threadIdx.x;   // 4096
    if (id >= 8 * DIM) return;
    int v = id >> 9, k = id & 511;
    int h = v >> 1, sd = v & 1;
    const float* Wr = W + ((size_t)h * DIM + k) * DHEAD;
    const float* av = a + h * 2 * DHEAD + sd * DHEAD;
    float s = 0.f;
#pragma unroll 4
    for (int f = 0; f < DHEAD; f++) s += Wr[f] * av[f];
    wt[(size_t)v * DIM + k] = s;
}

// ---------------- exact f32 attention logits: als[n][h] = x[n,:]·wt[h*2], ald likewise ----------------
__global__ __launch_bounds__(256) void k_als(const float* __restrict__ x,
                                             const float* __restrict__ wt,
                                             float* __restrict__ als, float* __restrict__ ald) {
    __shared__ float wl[8 * DIM];    // 16 KB
    for (int i = threadIdx.x; i < 8 * DIM / 4; i += 256)
        reinterpret_cast<float4*>(wl)[i] = reinterpret_cast<const float4*>(wt)[i];
    __syncthreads();
    int n = blockIdx.x * 4 + (threadIdx.x >> 6);
    if (n >= N_NODES) return;
    int lane = threadIdx.x & 63;
    const float4* xp = reinterpret_cast<const float4*>(x + (size_t)n * DIM + lane * 8);
    float4 x0 = xp[0], x1 = xp[1];
    float xv[8] = {x0.x, x0.y, x0.z, x0.w, x1.x, x1.y, x1.z, x1.w};
    float p[8] = {0.f, 0.f, 0.f, 0.f, 0.f, 0.f, 0.f, 0.f};
#pragma unroll
    for (int j = 0; j < 8; j++) {
        int k = lane * 8 + j;
#pragma unroll
        for (int v = 0; v < 8; v++) p[v] += xv[j] * wl[v * DIM + k];
    }
#pragma unroll
    for (int off = 1; off < 64; off <<= 1)
#pragma unroll
        for (int v = 0; v < 8; v++) p[v] += __shfl_xor(p[v], off);
    if (lane == 0) {
        float4 s = {p[0], p[2], p[4], p[6]};
        float4 d = {p[1], p[3], p[5], p[7]};
        *reinterpret_cast<float4*>(als + (size_t)n * 4) = s;
        *reinterpret_cast<float4*>(ald + (size_t)n * 4) = d;
    }
}

// ---------------- plain bf16 GEMM (R7 structure): H[m][c] = sum_k A[m][k] * Bt[c][k] ----------------
#define MFMA(a, b, c) __builtin_amdgcn_mfma_f32_16x16x32_bf16(a, b, c, 0, 0, 0)

__global__ __launch_bounds__(256, 8) void k_gemm_t(const unsigned short* __restrict__ A,
                                                   const unsigned short* __restrict__ Bt,
                                                   unsigned short* __restrict__ Hout) {
    __shared__ unsigned short lds[8192];   // 16 KB
    const int tid = threadIdx.x;

    // bijective XCD swizzle: 2504 = 8 * 313 exactly
    const int orig = blockIdx.x;
    const int wgid = (orig & 7) * 313 + (orig >> 3);
    const int mb = wgid >> 3, nb = wgid & 7;
    const int m0 = mb * BM, n0 = nb * BN;
    const int lane = tid & 63, wid = tid >> 6;
    const int wm = wid >> 1, wn = wid & 1;
    const int lr = lane & 15, kq = lane >> 4;

    f32x4 acc[2][2];
#pragma unroll
    for (int i = 0; i < 2; i++)
#pragma unroll
        for (int j = 0; j < 2; j++) acc[i][j] = (f32x4){0.f, 0.f, 0.f, 0.f};

#pragma unroll 1
    for (int t = 0; t < 8; t++) {
        const int k0 = t * BK;
#pragma unroll
        for (int it = 0; it < 4; it++) {
            const int region = it >> 1;              // 0=A 1=B
            int c = (it & 1) * 256 + tid;            // 0..511
            int row = c >> 3;                        // 0..63
            int sl = (c & 7) ^ (row & 7);            // inverse-swizzled source slot
            int koff = k0 + sl * 8;
            const unsigned short* srcp;
            if (region == 0) {
                int ar = m0 + row; ar = ar < N_NODES ? ar : N_NODES - 1;
                srcp = A + (size_t)ar * DIM + koff;
            } else {
                srcp = Bt + (size_t)(n0 + row) * DIM + koff;
            }
            unsigned short* lb = lds + region * 4096 + ((it & 1) * 256 + (tid & 192)) * 8;
            gl_lds16(srcp, lb);
        }
        asm volatile("s_waitcnt vmcnt(0)" ::: "memory");
        __syncthreads();

#pragma unroll
        for (int ks = 0; ks < 2; ks++) {
            bf16x8 ah[2], bh[2];
#pragma unroll
            for (int tm = 0; tm < 2; tm++) {
                int row = wm * 32 + tm * 16 + lr;
                int ph = (ks * 4 + kq) ^ (row & 7);
                ah[tm] = __builtin_bit_cast(bf16x8,
                    *reinterpret_cast<const short8*>(lds + row * 64 + ph * 8));
            }
#pragma unroll
            for (int tn = 0; tn < 2; tn++) {
                int col = wn * 32 + tn * 16 + lr;
                int ph = (ks * 4 + kq) ^ (col & 7);
                bh[tn] = __builtin_bit_cast(bf16x8,
                    *reinterpret_cast<const short8*>(lds + 4096 + col * 64 + ph * 8));
            }
#pragma unroll
            for (int tm = 0; tm < 2; tm++)
#pragma unroll
                for (int tn = 0; tn < 2; tn++)
                    acc[tm][tn] = MFMA(ah[tm], bh[tn], acc[tm][tn]);
        }
        if (t < 7) __syncthreads();
    }

#pragma unroll
    for (int tm = 0; tm < 2; tm++)
#pragma unroll
        for (int tn = 0; tn < 2; tn++) {
            int col = n0 + wn * 32 + tn * 16 + lr;
#pragma unroll
            for (int r4 = 0; r4 < 4; r4++) {
                int row = m0 + wm * 32 + tm * 16 + kq * 4 + r4;
                if (row < N_NODES) Hout[(size_t)row * DIM + col] = f32_to_bf16(acc[tm][tn][r4]);
            }
        }
}

// ---------------- single-pass softmax-free aggregation (src-sorted buckets) ----------------
#define EDGE_STEP(uu, ee, w0, w1)                                           \
    {                                                                       \
        float sc_ = (ee) + aldh;                                            \
        sc_ = fmaxf(sc_, NEG_SLOPE * sc_);                                  \
        float w_ = __expf(sc_);                                             \
        s += w_;                                                            \
        acc0 += w_ * bits_f32((w0) << 16);                                  \
        acc1 += w_ * bits_f32((w0) & 0xFFFF0000u);                          \
        acc2 += w_ * bits_f32((w1) << 16);                                  \
        acc3 += w_ * bits_f32((w1) & 0xFFFF0000u);                          \
    }

__global__ __launch_bounds__(256) void k_agg(const int* __restrict__ offsets,
                                             const int* __restrict__ csr_src,
                                             const float* __restrict__ als,
                                             const float* __restrict__ ald,
                                             const unsigned short* __restrict__ H,
                                             const float* __restrict__ bias,
                                             const float* __restrict__ resid,
                                             float* __restrict__ out_f32,
                                             unsigned short* __restrict__ out_b16) {
    int gw = (blockIdx.x * blockDim.x + threadIdx.x) >> 6;
    if (gw >= N_NODES * 2) return;
    int v = gw >> 1;
    int hf = gw & 1;
    int lane = threadIdx.x & 63;
    int c0 = hf * 256 + lane * 4;
    int hd = c0 >> 7;

    int beg = offsets[v], deg = offsets[v + 1] - beg;
    float aldh = ald[v * 4 + hd];
    const int* cp = csr_src + beg;

    float acc0 = 0.f, acc1 = 0.f, acc2 = 0.f, acc3 = 0.f, s = 0.f;
    int i = 0;
    for (; i + 4 <= deg; i += 4) {
        int u0 = cp[i], u1 = cp[i + 1], u2 = cp[i + 2], u3 = cp[i + 3];
        float e0 = als[u0 * 4 + hd];
        float e1 = als[u1 * 4 + hd];
        float e2 = als[u2 * 4 + hd];
        float e3 = als[u3 * 4 + hd];
        uint2 h0 = *reinterpret_cast<const uint2*>(H + (size_t)u0 * DIM + c0);
        uint2 h1 = *reinterpret_cast<const uint2*>(H + (size_t)u1 * DIM + c0);
        uint2 h2 = *reinterpret_cast<const uint2*>(H + (size_t)u2 * DIM + c0);
        uint2 h3 = *reinterpret_cast<const uint2*>(H + (size_t)u3 * DIM + c0);
        EDGE_STEP(u0, e0, h0.x, h0.y);
        EDGE_STEP(u1, e1, h1.x, h1.y);
        EDGE_STEP(u2, e2, h2.x, h2.y);
        EDGE_STEP(u3, e3, h3.x, h3.y);
    }
    for (; i < deg; i++) {
        int u0 = cp[i];
        float e0 = als[u0 * 4 + hd];
        uint2 h0 = *reinterpret_cast<const uint2*>(H + (size_t)u0 * DIM + c0);
        EDGE_STEP(u0, e0, h0.x, h0.y);
    }

    float inv = deg > 0 ? 1.0f / s : 0.f;
    float4 bv = *reinterpret_cast<const float4*>(bias + c0);
    float4 rv = *reinterpret_cast<const float4*>(resid + (size_t)v * DIM + c0);
    float o0 = acc0 * inv + bv.x;
    float o1 = acc1 * inv + bv.y;
    float o2 = acc2 * inv + bv.z;
    float o3 = acc3 * inv + bv.w;
    o0 = o0 > 0.f ? o0 : expm1f(o0);
    o1 = o1 > 0.f ? o1 : expm1f(o1);
    o2 = o2 > 0.f ? o2 : expm1f(o2);
    o3 = o3 > 0.f ? o3 : expm1f(o3);
    o0 += rv.x; o1 += rv.y; o2 += rv.z; o3 += rv.w;
    float4 ov = {o0, o1, o2, o3};
    *reinterpret_cast<float4*>(out_f32 + (size_t)v * DIM + c0) = ov;
    if (out_b16) {
        ushort4 ob = {f32_to_bf16(o0), f32_to_bf16(o1), f32_to_bf16(o2), f32_to_bf16(o3)};
        *reinterpret_cast<ushort4*>(out_b16 + (size_t)v * DIM + c0) = ob;
    }
}

extern "C" void kernel_launch(void* const* d_in, const int* in_sizes, int n_in,
                              void* d_out, int out_size, void* d_ws, size_t ws_size,
                              hipStream_t stream) {
    const float* x = (const float*)d_in[0];
    const int* ei = (const int*)d_in[1];
    const int* src = ei;
    const int* dst = ei + N_EDGES;
    const float* W1 = (const float*)d_in[5];
    const float* a1 = (const float*)d_in[6];
    const float* b1 = (const float*)d_in[7];
    const float* W2 = (const float*)d_in[8];
    const float* a2 = (const float*)d_in[9];
    const float* b2 = (const float*)d_in[10];

    char* ws = (char*)d_ws;
    size_t off = 0;
    auto alloc = [&](size_t bytes) -> void* {
        void* p = ws + off;
        off += (bytes + 255) & ~(size_t)255;
        return p;
    };
    unsigned short* xb   = (unsigned short*)alloc((size_t)N_NODES * DIM * 2);
    unsigned short* h    = (unsigned short*)alloc((size_t)N_NODES * DIM * 2);
    float* x1            = (float*)alloc((size_t)N_NODES * DIM * 4);
    float* als           = (float*)alloc((size_t)N_NODES * 8 * 4);  // als | ald contiguous
    float* ald           = als + (size_t)N_NODES * 4;
    unsigned short* B1   = (unsigned short*)alloc((size_t)DIM * DIM * 2);
    unsigned short* B2   = (unsigned short*)alloc((size_t)DIM * DIM * 2);
    float* wt1           = (float*)alloc((size_t)8 * DIM * 4);
    float* wt2           = (float*)alloc((size_t)8 * DIM * 4);
    int* offsets         = (int*)alloc((size_t)(N_NODES + 1) * 4);
    int* cursor          = (int*)alloc((size_t)N_NODES * 4);
    int* counts          = (int*)alloc((size_t)N_NODES * 4);
    int* soff            = (int*)alloc((size_t)(N_NODES + 1) * 4);
    int* scursor         = (int*)alloc((size_t)N_NODES * 4);
    int* scounts         = (int*)alloc((size_t)N_NODES * 4);
    int* csr_src         = (int*)alloc((size_t)N_EDGES * 4);
    int* sdst            = (int*)alloc((size_t)N_EDGES * 4);
    int* ssrc            = (int*)alloc((size_t)N_EDGES * 4);

    const int EB = (N_EDGES + 255) / 256;

    // ---- edge sort by src, then dst-CSR fill in src order ----
    hipMemsetAsync(counts, 0, (size_t)N_NODES * 4, stream);
    hipMemsetAsync(scounts, 0, (size_t)N_NODES * 4, stream);
    k_hist<<<EB, 256, 0, stream>>>(dst, counts);
    k_hist<<<EB, 256, 0, stream>>>(src, scounts);
    k_scan<<<1, 1024, 0, stream>>>(counts, offsets, cursor);
    k_scan<<<1, 1024, 0, stream>>>(scounts, soff, scursor);
    k_scatter<<<EB, 256, 0, stream>>>(src, dst, scursor, sdst, ssrc);
    k_fill<<<EB, 256, 0, stream>>>(sdst, ssrc, cursor, csr_src);

    // casts / weight prep
    k_cast<<<(N_NODES * DIM / 8 + 255) / 256, 256, 0, stream>>>(x, xb, N_NODES * DIM / 8);
    k_transW<<<(512 * 64 + 255) / 256, 256, 0, stream>>>(W1, B1);
    k_transW<<<(512 * 64 + 255) / 256, 256, 0, stream>>>(W2, B2);
    k_wtilde<<<(8 * DIM + 255) / 256, 256, 0, stream>>>(W1, a1, wt1);
    k_wtilde<<<(8 * DIM + 255) / 256, 256, 0, stream>>>(W2, a2, wt2);

    const int GEMM_BLOCKS = ((N_NODES + BM - 1) / BM) * (DIM / BN);  // 313 * 8 = 2504
    const int ALS_BLOCKS = (N_NODES + 3) / 4;                        // 5000
    const int AGG_BLOCKS = (N_NODES * 2 + 3) / 4;                    // 10000

    // ---- layer 1 ----
    k_gemm_t<<<GEMM_BLOCKS, 256, 0, stream>>>(xb, B1, h);
    k_als<<<ALS_BLOCKS, 256, 0, stream>>>(x, wt1, als, ald);
    k_agg<<<AGG_BLOCKS, 256, 0, stream>>>(offsets, csr_src, als, ald, h, b1, x, x1, xb);

    // ---- layer 2 ----
    k_gemm_t<<<GEMM_BLOCKS, 256, 0, stream>>>(xb, B2, h);
    k_als<<<ALS_BLOCKS, 256, 0, stream>>>(x1, wt2, als, ald);
    k_agg<<<AGG_BLOCKS, 256, 0, stream>>>(offsets, csr_src, als, ald, h, b2, x1, (float*)d_out, nullptr);
}

// Round 10
// 287.654 us; speedup vs baseline: 1.2872x; 1.2872x over previous
//
#include <hip/hip_runtime.h>
#include <hip/hip_bf16.h>
#include <math.h>

#define N_NODES 20000
#define N_EDGES 320000
#define DIM 512
#define HEADS 4
#define DHEAD 128
#define NEG_SLOPE 0.2f
#define BM 64
#define BN 64
#define BK 64

typedef __attribute__((ext_vector_type(8))) short short8;
typedef __attribute__((ext_vector_type(8))) __bf16 bf16x8;
typedef __attribute__((ext_vector_type(4))) float f32x4;

static __device__ __forceinline__ unsigned short f32_to_bf16(float f) {
    union { float f; unsigned u; } v; v.f = f;
    unsigned u = v.u;
    u += 0x7FFFu + ((u >> 16) & 1u);   // round-to-nearest-even
    return (unsigned short)(u >> 16);
}
static __device__ __forceinline__ float bf16_to_f32(unsigned short s) {
    union { unsigned u; float f; } v; v.u = ((unsigned)s) << 16;
    return v.f;
}
static __device__ __forceinline__ float bits_f32(unsigned u) {
    union { unsigned u; float f; } v; v.u = u;
    return v.f;
}

static __device__ __forceinline__ void gl_lds16(const unsigned short* g, unsigned short* l) {
    __builtin_amdgcn_global_load_lds(
        (const __attribute__((address_space(1))) unsigned int*)g,
        (__attribute__((address_space(3))) unsigned int*)l, 16, 0, 0);
}

// ---------------- CSR build (R7 form) ----------------
__global__ void k_hist(const int* __restrict__ dst, int* __restrict__ counts) {
    int e = blockIdx.x * blockDim.x + threadIdx.x;
    if (e >= N_EDGES) return;
    atomicAdd(&counts[dst[e]], 1);
}

__global__ void k_scan(const int* __restrict__ counts, int* __restrict__ offsets,
                       int* __restrict__ cursor) {
    __shared__ int lds[1024];
    int t = threadIdx.x;
    const int CH = (N_NODES + 1023) / 1024;   // 20
    int base = t * CH;
    int sum = 0;
    for (int j = 0; j < CH; j++) {
        int i = base + j;
        if (i < N_NODES) sum += counts[i];
    }
    lds[t] = sum;
    __syncthreads();
    for (int off = 1; off < 1024; off <<= 1) {
        int other = (t >= off) ? lds[t - off] : 0;
        __syncthreads();
        lds[t] += other;
        __syncthreads();
    }
    int excl = lds[t] - sum;
    int run = excl;
    for (int j = 0; j < CH; j++) {
        int i = base + j;
        if (i < N_NODES) {
            offsets[i] = run;
            cursor[i] = run;
            run += counts[i];
        }
    }
    if (t == 0) offsets[N_NODES] = N_EDGES;
}

__global__ void k_fill(const int* __restrict__ src, const int* __restrict__ dst,
                       int* __restrict__ cursor, int* __restrict__ csr_src) {
    int e = blockIdx.x * blockDim.x + threadIdx.x;
    if (e >= N_EDGES) return;
    int d = dst[e];
    int p = atomicAdd(&cursor[d], 1);
    csr_src[p] = src[e];
}

// ---------------- cast x -> bf16 row-major ----------------
__global__ void k_cast(const float* __restrict__ in, unsigned short* __restrict__ out, int n8) {
    int i = blockIdx.x * blockDim.x + threadIdx.x;
    if (i >= n8) return;
    const float4* p = reinterpret_cast<const float4*>(in) + (size_t)i * 2;
    float4 a = p[0], b = p[1];
    short8 o;
    o[0] = (short)f32_to_bf16(a.x); o[1] = (short)f32_to_bf16(a.y);
    o[2] = (short)f32_to_bf16(a.z); o[3] = (short)f32_to_bf16(a.w);
    o[4] = (short)f32_to_bf16(b.x); o[5] = (short)f32_to_bf16(b.y);
    o[6] = (short)f32_to_bf16(b.z); o[7] = (short)f32_to_bf16(b.w);
    *reinterpret_cast<short8*>(out + (size_t)i * 8) = o;
}

// W: (H, D, DH) f32 -> Bt: [col][k] bf16, col=h*128+f, k over D
__global__ void k_transW(const float* __restrict__ W, unsigned short* __restrict__ Bt) {
    int id = blockIdx.x * blockDim.x + threadIdx.x;
    if (id >= 512 * 64) return;
    int col = id >> 6;
    int kg = id & 63;
    int h = col >> 7;
    int f = col & 127;
    short8 o;
#pragma unroll
    for (int j = 0; j < 8; j++) {
        int k = kg * 8 + j;
        o[j] = (short)f32_to_bf16(W[(size_t)h * DIM * DHEAD + (size_t)k * DHEAD + f]);
    }
    *reinterpret_cast<short8*>(Bt + (size_t)col * DIM + kg * 8) = o;
}

// ---------------- w-tilde: wt[v][k] = sum_f W[h][k][f] * a[h][sd*128+f], v=h*2+sd ----------------
__global__ void k_wtilde(const float* __restrict__ W, const float* __restrict__ a,
                         float* __restrict__ wt) {
    int id = blockIdx.x * blockDim.x + threadIdx.x;   // 4096
    if (id >= 8 * DIM) return;
    int v = id >> 9, k = id & 511;
    int h = v >> 1, sd = v & 1;
    const float* Wr = W + ((size_t)h * DIM + k) * DHEAD;
    const float* av = a + h * 2 * DHEAD + sd * DHEAD;
    float s = 0.f;
#pragma unroll 4
    for (int f = 0; f < DHEAD; f++) s += Wr[f] * av[f];
    wt[(size_t)v * DIM + k] = s;
}

// ---------------- attention logits from bf16 x: als[n][h] = x[n,:]·wt[h*2] ----------------
__global__ __launch_bounds__(256) void k_als(const unsigned short* __restrict__ xb,
                                             const float* __restrict__ wt,
                                             float* __restrict__ als, float* __restrict__ ald) {
    __shared__ float wl[8 * DIM];    // 16 KB
    for (int i = threadIdx.x; i < 8 * DIM / 4; i += 256)
        reinterpret_cast<float4*>(wl)[i] = reinterpret_cast<const float4*>(wt)[i];
    __syncthreads();
    int n = blockIdx.x * 4 + (threadIdx.x >> 6);
    if (n >= N_NODES) return;
    int lane = threadIdx.x & 63;
    short8 xv8 = *reinterpret_cast<const short8*>(xb + (size_t)n * DIM + lane * 8);
    float xv[8];
#pragma unroll
    for (int j = 0; j < 8; j++) xv[j] = bf16_to_f32((unsigned short)xv8[j]);
    float p[8] = {0.f, 0.f, 0.f, 0.f, 0.f, 0.f, 0.f, 0.f};
#pragma unroll
    for (int j = 0; j < 8; j++) {
        int k = lane * 8 + j;
#pragma unroll
        for (int v = 0; v < 8; v++) p[v] += xv[j] * wl[v * DIM + k];
    }
#pragma unroll
    for (int off = 1; off < 64; off <<= 1)
#pragma unroll
        for (int v = 0; v < 8; v++) p[v] += __shfl_xor(p[v], off);
    if (lane == 0) {
        float4 s = {p[0], p[2], p[4], p[6]};
        float4 d = {p[1], p[3], p[5], p[7]};
        *reinterpret_cast<float4*>(als + (size_t)n * 4) = s;
        *reinterpret_cast<float4*>(ald + (size_t)n * 4) = d;
    }
}

// ---------------- plain bf16 GEMM (R7 structure): H[m][c] = sum_k A[m][k] * Bt[c][k] ----------------
#define MFMA(a, b, c) __builtin_amdgcn_mfma_f32_16x16x32_bf16(a, b, c, 0, 0, 0)

__global__ __launch_bounds__(256, 8) void k_gemm_t(const unsigned short* __restrict__ A,
                                                   const unsigned short* __restrict__ Bt,
                                                   unsigned short* __restrict__ Hout) {
    __shared__ unsigned short lds[8192];   // 16 KB
    const int tid = threadIdx.x;

    // bijective XCD swizzle: 2504 = 8 * 313 exactly
    const int orig = blockIdx.x;
    const int wgid = (orig & 7) * 313 + (orig >> 3);
    const int mb = wgid >> 3, nb = wgid & 7;
    const int m0 = mb * BM, n0 = nb * BN;
    const int lane = tid & 63, wid = tid >> 6;
    const int wm = wid >> 1, wn = wid & 1;
    const int lr = lane & 15, kq = lane >> 4;

    f32x4 acc[2][2];
#pragma unroll
    for (int i = 0; i < 2; i++)
#pragma unroll
        for (int j = 0; j < 2; j++) acc[i][j] = (f32x4){0.f, 0.f, 0.f, 0.f};

#pragma unroll 1
    for (int t = 0; t < 8; t++) {
        const int k0 = t * BK;
#pragma unroll
        for (int it = 0; it < 4; it++) {
            const int region = it >> 1;              // 0=A 1=B
            int c = (it & 1) * 256 + tid;            // 0..511
            int row = c >> 3;                        // 0..63
            int sl = (c & 7) ^ (row & 7);            // inverse-swizzled source slot
            int koff = k0 + sl * 8;
            const unsigned short* srcp;
            if (region == 0) {
                int ar = m0 + row; ar = ar < N_NODES ? ar : N_NODES - 1;
                srcp = A + (size_t)ar * DIM + koff;
            } else {
                srcp = Bt + (size_t)(n0 + row) * DIM + koff;
            }
            unsigned short* lb = lds + region * 4096 + ((it & 1) * 256 + (tid & 192)) * 8;
            gl_lds16(srcp, lb);
        }
        asm volatile("s_waitcnt vmcnt(0)" ::: "memory");
        __syncthreads();

#pragma unroll
        for (int ks = 0; ks < 2; ks++) {
            bf16x8 ah[2], bh[2];
#pragma unroll
            for (int tm = 0; tm < 2; tm++) {
                int row = wm * 32 + tm * 16 + lr;
                int ph = (ks * 4 + kq) ^ (row & 7);
                ah[tm] = __builtin_bit_cast(bf16x8,
                    *reinterpret_cast<const short8*>(lds + row * 64 + ph * 8));
            }
#pragma unroll
            for (int tn = 0; tn < 2; tn++) {
                int col = wn * 32 + tn * 16 + lr;
                int ph = (ks * 4 + kq) ^ (col & 7);
                bh[tn] = __builtin_bit_cast(bf16x8,
                    *reinterpret_cast<const short8*>(lds + 4096 + col * 64 + ph * 8));
            }
#pragma unroll
            for (int tm = 0; tm < 2; tm++)
#pragma unroll
                for (int tn = 0; tn < 2; tn++)
                    acc[tm][tn] = MFMA(ah[tm], bh[tn], acc[tm][tn]);
        }
        if (t < 7) __syncthreads();
    }

#pragma unroll
    for (int tm = 0; tm < 2; tm++)
#pragma unroll
        for (int tn = 0; tn < 2; tn++) {
            int col = n0 + wn * 32 + tn * 16 + lr;
#pragma unroll
            for (int r4 = 0; r4 < 4; r4++) {
                int row = m0 + wm * 32 + tm * 16 + kq * 4 + r4;
                if (row < N_NODES) Hout[(size_t)row * DIM + col] = f32_to_bf16(acc[tm][tn][r4]);
            }
        }
}

// ---------------- single-pass aggregation: ONE wave per node, uint4 h loads ----------------
// lane covers 8 cols at c0 = lane*8; head hd = lane>>4. alpha = exp(leaky(e))/sum.
#define EDGE_STEP(ee, hq)                                                   \
    {                                                                       \
        float sc_ = (ee) + aldh;                                            \
        sc_ = fmaxf(sc_, NEG_SLOPE * sc_);                                  \
        float w_ = __expf(sc_);                                             \
        s += w_;                                                            \
        acc[0] += w_ * bits_f32((hq).x << 16);                              \
        acc[1] += w_ * bits_f32((hq).x & 0xFFFF0000u);                      \
        acc[2] += w_ * bits_f32((hq).y << 16);                              \
        acc[3] += w_ * bits_f32((hq).y & 0xFFFF0000u);                      \
        acc[4] += w_ * bits_f32((hq).z << 16);                              \
        acc[5] += w_ * bits_f32((hq).z & 0xFFFF0000u);                      \
        acc[6] += w_ * bits_f32((hq).w << 16);                              \
        acc[7] += w_ * bits_f32((hq).w & 0xFFFF0000u);                      \
    }

__global__ __launch_bounds__(256) void k_agg(const int* __restrict__ offsets,
                                             const int* __restrict__ csr_src,
                                             const float* __restrict__ als,
                                             const float* __restrict__ ald,
                                             const unsigned short* __restrict__ H,
                                             const float* __restrict__ bias,
                                             const float* __restrict__ resid_f32,
                                             const unsigned short* __restrict__ resid_b16,
                                             float* __restrict__ out_f32,
                                             unsigned short* __restrict__ out_b16) {
    int v = (blockIdx.x * blockDim.x + threadIdx.x) >> 6;
    if (v >= N_NODES) return;
    int lane = threadIdx.x & 63;
    int c0 = lane * 8;
    int hd = lane >> 4;

    int beg = offsets[v], deg = offsets[v + 1] - beg;
    float aldh = ald[v * 4 + hd];
    const int* cp = csr_src + beg;

    float acc[8] = {0.f, 0.f, 0.f, 0.f, 0.f, 0.f, 0.f, 0.f};
    float s = 0.f;
    int i = 0;
    for (; i + 4 <= deg; i += 4) {
        int u0 = cp[i], u1 = cp[i + 1], u2 = cp[i + 2], u3 = cp[i + 3];
        float e0 = als[u0 * 4 + hd];
        float e1 = als[u1 * 4 + hd];
        float e2 = als[u2 * 4 + hd];
        float e3 = als[u3 * 4 + hd];
        uint4 h0 = *reinterpret_cast<const uint4*>(H + (size_t)u0 * DIM + c0);
        uint4 h1 = *reinterpret_cast<const uint4*>(H + (size_t)u1 * DIM + c0);
        uint4 h2 = *reinterpret_cast<const uint4*>(H + (size_t)u2 * DIM + c0);
        uint4 h3 = *reinterpret_cast<const uint4*>(H + (size_t)u3 * DIM + c0);
        EDGE_STEP(e0, h0);
        EDGE_STEP(e1, h1);
        EDGE_STEP(e2, h2);
        EDGE_STEP(e3, h3);
    }
    for (; i < deg; i++) {
        int u0 = cp[i];
        float e0 = als[u0 * 4 + hd];
        uint4 h0 = *reinterpret_cast<const uint4*>(H + (size_t)u0 * DIM + c0);
        EDGE_STEP(e0, h0);
    }

    float inv = deg > 0 ? 1.0f / s : 0.f;
    const float4* bp = reinterpret_cast<const float4*>(bias + c0);
    float4 b0 = bp[0], b1 = bp[1];
    float bv[8] = {b0.x, b0.y, b0.z, b0.w, b1.x, b1.y, b1.z, b1.w};
    float o[8];
#pragma unroll
    for (int j = 0; j < 8; j++) {
        float t = acc[j] * inv + bv[j];
        o[j] = t > 0.f ? t : expm1f(t);
    }
    if (resid_f32) {
        const float4* rp = reinterpret_cast<const float4*>(resid_f32 + (size_t)v * DIM + c0);
        float4 r0 = rp[0], r1 = rp[1];
        o[0] += r0.x; o[1] += r0.y; o[2] += r0.z; o[3] += r0.w;
        o[4] += r1.x; o[5] += r1.y; o[6] += r1.z; o[7] += r1.w;
    } else {
        short8 rv = *reinterpret_cast<const short8*>(resid_b16 + (size_t)v * DIM + c0);
#pragma unroll
        for (int j = 0; j < 8; j++) o[j] += bf16_to_f32((unsigned short)rv[j]);
    }
    if (out_f32) {
        float4 w0 = {o[0], o[1], o[2], o[3]};
        float4 w1 = {o[4], o[5], o[6], o[7]};
        float4* op = reinterpret_cast<float4*>(out_f32 + (size_t)v * DIM + c0);
        op[0] = w0;
        op[1] = w1;
    }
    if (out_b16) {
        short8 ob;
#pragma unroll
        for (int j = 0; j < 8; j++) ob[j] = (short)f32_to_bf16(o[j]);
        *reinterpret_cast<short8*>(out_b16 + (size_t)v * DIM + c0) = ob;
    }
}

extern "C" void kernel_launch(void* const* d_in, const int* in_sizes, int n_in,
                              void* d_out, int out_size, void* d_ws, size_t ws_size,
                              hipStream_t stream) {
    const float* x = (const float*)d_in[0];
    const int* ei = (const int*)d_in[1];
    const int* src = ei;
    const int* dst = ei + N_EDGES;
    const float* W1 = (const float*)d_in[5];
    const float* a1 = (const float*)d_in[6];
    const float* b1 = (const float*)d_in[7];
    const float* W2 = (const float*)d_in[8];
    const float* a2 = (const float*)d_in[9];
    const float* b2 = (const float*)d_in[10];

    char* ws = (char*)d_ws;
    size_t off = 0;
    auto alloc = [&](size_t bytes) -> void* {
        void* p = ws + off;
        off += (bytes + 255) & ~(size_t)255;
        return p;
    };
    unsigned short* xb   = (unsigned short*)alloc((size_t)N_NODES * DIM * 2);  // x bf16, then x1 bf16
    unsigned short* h    = (unsigned short*)alloc((size_t)N_NODES * DIM * 2);
    float* als           = (float*)alloc((size_t)N_NODES * 8 * 4);  // als | ald contiguous
    float* ald           = als + (size_t)N_NODES * 4;
    unsigned short* B1   = (unsigned short*)alloc((size_t)DIM * DIM * 2);
    unsigned short* B2   = (unsigned short*)alloc((size_t)DIM * DIM * 2);
    float* wt1           = (float*)alloc((size_t)8 * DIM * 4);
    float* wt2           = (float*)alloc((size_t)8 * DIM * 4);
    int* offsets         = (int*)alloc((size_t)(N_NODES + 1) * 4);
    int* cursor          = (int*)alloc((size_t)N_NODES * 4);
    int* counts          = (int*)alloc((size_t)N_NODES * 4);
    int* csr_src         = (int*)alloc((size_t)N_EDGES * 4);

    // CSR build (shared by both layers)
    hipMemsetAsync(counts, 0, (size_t)N_NODES * 4, stream);
    k_hist<<<(N_EDGES + 255) / 256, 256, 0, stream>>>(dst, counts);
    k_scan<<<1, 1024, 0, stream>>>(counts, offsets, cursor);
    k_fill<<<(N_EDGES + 255) / 256, 256, 0, stream>>>(src, dst, cursor, csr_src);

    // casts / weight prep
    k_cast<<<(N_NODES * DIM / 8 + 255) / 256, 256, 0, stream>>>(x, xb, N_NODES * DIM / 8);
    k_transW<<<(512 * 64 + 255) / 256, 256, 0, stream>>>(W1, B1);
    k_transW<<<(512 * 64 + 255) / 256, 256, 0, stream>>>(W2, B2);
    k_wtilde<<<(8 * DIM + 255) / 256, 256, 0, stream>>>(W1, a1, wt1);
    k_wtilde<<<(8 * DIM + 255) / 256, 256, 0, stream>>>(W2, a2, wt2);

    const int GEMM_BLOCKS = ((N_NODES + BM - 1) / BM) * (DIM / BN);  // 313 * 8 = 2504
    const int ALS_BLOCKS = (N_NODES + 3) / 4;                        // 5000
    const int AGG_BLOCKS = (N_NODES + 3) / 4;                        // 5000 (1 wave/node)

    // ---- layer 1 ----
    k_gemm_t<<<GEMM_BLOCKS, 256, 0, stream>>>(xb, B1, h);
    k_als<<<ALS_BLOCKS, 256, 0, stream>>>(xb, wt1, als, ald);
    // resid = x (f32); output only bf16 x1 (overwrites xb; safe: k_agg doesn't read xb)
    k_agg<<<AGG_BLOCKS, 256, 0, stream>>>(offsets, csr_src, als, ald, h, b1,
                                          x, nullptr, nullptr, xb);

    // ---- layer 2 ----
    k_gemm_t<<<GEMM_BLOCKS, 256, 0, stream>>>(xb, B2, h);
    k_als<<<ALS_BLOCKS, 256, 0, stream>>>(xb, wt2, als, ald);
    // resid = x1 (bf16); output f32 d_out
    k_agg<<<AGG_BLOCKS, 256, 0, stream>>>(offsets, csr_src, als, ald, h, b2,
                                          nullptr, xb, (float*)d_out, nullptr);
}

// Round 11
// 281.617 us; speedup vs baseline: 1.3148x; 1.0214x over previous
//
#include <hip/hip_runtime.h>
#include <hip/hip_bf16.h>
#include <math.h>

#define N_NODES 20000
#define N_EDGES 320000
#define DIM 512
#define HEADS 4
#define DHEAD 128
#define NEG_SLOPE 0.2f
#define BM 64
#define BN 64
#define BK 64

typedef __attribute__((ext_vector_type(8))) short short8;
typedef __attribute__((ext_vector_type(8))) __bf16 bf16x8;
typedef __attribute__((ext_vector_type(4))) float f32x4;

static __device__ __forceinline__ unsigned short f32_to_bf16(float f) {
    union { float f; unsigned u; } v; v.f = f;
    unsigned u = v.u;
    u += 0x7FFFu + ((u >> 16) & 1u);   // round-to-nearest-even
    return (unsigned short)(u >> 16);
}
static __device__ __forceinline__ float bf16_to_f32(unsigned short s) {
    union { unsigned u; float f; } v; v.u = ((unsigned)s) << 16;
    return v.f;
}
static __device__ __forceinline__ float bits_f32(unsigned u) {
    union { unsigned u; float f; } v; v.u = u;
    return v.f;
}

static __device__ __forceinline__ void gl_lds16(const unsigned short* g, unsigned short* l) {
    __builtin_amdgcn_global_load_lds(
        (const __attribute__((address_space(1))) unsigned int*)g,
        (__attribute__((address_space(3))) unsigned int*)l, 16, 0, 0);
}

// ---------------- fused prologue: cast | transW x2 | wtilde x2 | hist ----------------
// block roles: [0,5000) cast; [5000,5128) transW1; [5128,5256) transW2;
//              [5256,5272) wtilde1; [5272,5288) wtilde2; [5288,6538) hist
static __device__ __forceinline__ void do_cast(const float* in, unsigned short* out, int i) {
    const float4* p = reinterpret_cast<const float4*>(in) + (size_t)i * 2;
    float4 a = p[0], b = p[1];
    short8 o;
    o[0] = (short)f32_to_bf16(a.x); o[1] = (short)f32_to_bf16(a.y);
    o[2] = (short)f32_to_bf16(a.z); o[3] = (short)f32_to_bf16(a.w);
    o[4] = (short)f32_to_bf16(b.x); o[5] = (short)f32_to_bf16(b.y);
    o[6] = (short)f32_to_bf16(b.z); o[7] = (short)f32_to_bf16(b.w);
    *reinterpret_cast<short8*>(out + (size_t)i * 8) = o;
}
static __device__ __forceinline__ void do_transW(const float* W, unsigned short* Bt, int id) {
    int col = id >> 6;
    int kg = id & 63;
    int h = col >> 7;
    int f = col & 127;
    short8 o;
#pragma unroll
    for (int j = 0; j < 8; j++) {
        int k = kg * 8 + j;
        o[j] = (short)f32_to_bf16(W[(size_t)h * DIM * DHEAD + (size_t)k * DHEAD + f]);
    }
    *reinterpret_cast<short8*>(Bt + (size_t)col * DIM + kg * 8) = o;
}
static __device__ __forceinline__ void do_wtilde(const float* W, const float* a, float* wt, int id) {
    int v = id >> 9, k = id & 511;
    int h = v >> 1, sd = v & 1;
    const float* Wr = W + ((size_t)h * DIM + k) * DHEAD;
    const float* av = a + h * 2 * DHEAD + sd * DHEAD;
    float s = 0.f;
#pragma unroll 4
    for (int f = 0; f < DHEAD; f++) s += Wr[f] * av[f];
    wt[(size_t)v * DIM + k] = s;
}

__global__ void k_prep(const float* __restrict__ x, unsigned short* __restrict__ xb,
                       const float* __restrict__ W1, unsigned short* __restrict__ B1,
                       const float* __restrict__ W2, unsigned short* __restrict__ B2,
                       const float* __restrict__ a1, float* __restrict__ wt1,
                       const float* __restrict__ a2, float* __restrict__ wt2,
                       const int* __restrict__ dst, int* __restrict__ counts) {
    int b = blockIdx.x, tid = threadIdx.x;
    if (b < 5000) {
        do_cast(x, xb, b * 256 + tid);
    } else if (b < 5128) {
        do_transW(W1, B1, (b - 5000) * 256 + tid);
    } else if (b < 5256) {
        do_transW(W2, B2, (b - 5128) * 256 + tid);
    } else if (b < 5272) {
        do_wtilde(W1, a1, wt1, (b - 5256) * 256 + tid);
    } else if (b < 5288) {
        do_wtilde(W2, a2, wt2, (b - 5272) * 256 + tid);
    } else {
        int e = (b - 5288) * 256 + tid;
        if (e < N_EDGES) atomicAdd(&counts[dst[e]], 1);
    }
}

// ---------------- CSR build ----------------
__global__ void k_scan(const int* __restrict__ counts, int* __restrict__ offsets,
                       int* __restrict__ cursor) {
    __shared__ int lds[1024];
    int t = threadIdx.x;
    const int CH = (N_NODES + 1023) / 1024;   // 20
    int base = t * CH;
    int sum = 0;
    for (int j = 0; j < CH; j++) {
        int i = base + j;
        if (i < N_NODES) sum += counts[i];
    }
    lds[t] = sum;
    __syncthreads();
    for (int off = 1; off < 1024; off <<= 1) {
        int other = (t >= off) ? lds[t - off] : 0;
        __syncthreads();
        lds[t] += other;
        __syncthreads();
    }
    int excl = lds[t] - sum;
    int run = excl;
    for (int j = 0; j < CH; j++) {
        int i = base + j;
        if (i < N_NODES) {
            offsets[i] = run;
            cursor[i] = run;
            run += counts[i];
        }
    }
    if (t == 0) offsets[N_NODES] = N_EDGES;
}

__global__ void k_fill(const int* __restrict__ src, const int* __restrict__ dst,
                       int* __restrict__ cursor, int* __restrict__ csr_src,
                       int* __restrict__ csr_dst) {
    int e = blockIdx.x * blockDim.x + threadIdx.x;
    if (e >= N_EDGES) return;
    int d = dst[e];
    int p = atomicAdd(&cursor[d], 1);
    csr_src[p] = src[e];
    csr_dst[p] = d;
}

// ---------------- attention logits from bf16 x: als[n][h] = x[n,:]·wt[h*2] ----------------
__global__ __launch_bounds__(256) void k_als(const unsigned short* __restrict__ xb,
                                             const float* __restrict__ wt,
                                             float* __restrict__ als, float* __restrict__ ald) {
    __shared__ float wl[8 * DIM];    // 16 KB
    for (int i = threadIdx.x; i < 8 * DIM / 4; i += 256)
        reinterpret_cast<float4*>(wl)[i] = reinterpret_cast<const float4*>(wt)[i];
    __syncthreads();
    int n = blockIdx.x * 4 + (threadIdx.x >> 6);
    if (n >= N_NODES) return;
    int lane = threadIdx.x & 63;
    short8 xv8 = *reinterpret_cast<const short8*>(xb + (size_t)n * DIM + lane * 8);
    float xv[8];
#pragma unroll
    for (int j = 0; j < 8; j++) xv[j] = bf16_to_f32((unsigned short)xv8[j]);
    float p[8] = {0.f, 0.f, 0.f, 0.f, 0.f, 0.f, 0.f, 0.f};
#pragma unroll
    for (int j = 0; j < 8; j++) {
        int k = lane * 8 + j;
#pragma unroll
        for (int v = 0; v < 8; v++) p[v] += xv[j] * wl[v * DIM + k];
    }
#pragma unroll
    for (int off = 1; off < 64; off <<= 1)
#pragma unroll
        for (int v = 0; v < 8; v++) p[v] += __shfl_xor(p[v], off);
    if (lane == 0) {
        float4 s = {p[0], p[2], p[4], p[6]};
        float4 d = {p[1], p[3], p[5], p[7]};
        *reinterpret_cast<float4*>(als + (size_t)n * 4) = s;
        *reinterpret_cast<float4*>(ald + (size_t)n * 4) = d;
    }
}

// ---------------- edge weights in CSR order: wbuf[p][h] = exp(leaky(als[u][h]+ald[v][h])) ----------------
__global__ __launch_bounds__(256) void k_edgew(const int* __restrict__ csr_src,
                                               const int* __restrict__ csr_dst,
                                               const float* __restrict__ als,
                                               const float* __restrict__ ald,
                                               float* __restrict__ wbuf) {
    int p = blockIdx.x * blockDim.x + threadIdx.x;
    if (p >= N_EDGES) return;
    int u = csr_src[p], v = csr_dst[p];
    float4 as = *reinterpret_cast<const float4*>(als + (size_t)u * 4);
    float4 ad = *reinterpret_cast<const float4*>(ald + (size_t)v * 4);
    float4 w;
    float sc;
    sc = as.x + ad.x; sc = fmaxf(sc, NEG_SLOPE * sc); w.x = __expf(sc);
    sc = as.y + ad.y; sc = fmaxf(sc, NEG_SLOPE * sc); w.y = __expf(sc);
    sc = as.z + ad.z; sc = fmaxf(sc, NEG_SLOPE * sc); w.z = __expf(sc);
    sc = as.w + ad.w; sc = fmaxf(sc, NEG_SLOPE * sc); w.w = __expf(sc);
    *reinterpret_cast<float4*>(wbuf + (size_t)p * 4) = w;
}

// ---------------- plain bf16 GEMM (R7 structure): H[m][c] = sum_k A[m][k] * Bt[c][k] ----------------
#define MFMA(a, b, c) __builtin_amdgcn_mfma_f32_16x16x32_bf16(a, b, c, 0, 0, 0)

__global__ __launch_bounds__(256, 8) void k_gemm_t(const unsigned short* __restrict__ A,
                                                   const unsigned short* __restrict__ Bt,
                                                   unsigned short* __restrict__ Hout) {
    __shared__ unsigned short lds[8192];   // 16 KB
    const int tid = threadIdx.x;

    // bijective XCD swizzle: 2504 = 8 * 313 exactly
    const int orig = blockIdx.x;
    const int wgid = (orig & 7) * 313 + (orig >> 3);
    const int mb = wgid >> 3, nb = wgid & 7;
    const int m0 = mb * BM, n0 = nb * BN;
    const int lane = tid & 63, wid = tid >> 6;
    const int wm = wid >> 1, wn = wid & 1;
    const int lr = lane & 15, kq = lane >> 4;

    f32x4 acc[2][2];
#pragma unroll
    for (int i = 0; i < 2; i++)
#pragma unroll
        for (int j = 0; j < 2; j++) acc[i][j] = (f32x4){0.f, 0.f, 0.f, 0.f};

#pragma unroll 1
    for (int t = 0; t < 8; t++) {
        const int k0 = t * BK;
#pragma unroll
        for (int it = 0; it < 4; it++) {
            const int region = it >> 1;              // 0=A 1=B
            int c = (it & 1) * 256 + tid;            // 0..511
            int row = c >> 3;                        // 0..63
            int sl = (c & 7) ^ (row & 7);            // inverse-swizzled source slot
            int koff = k0 + sl * 8;
            const unsigned short* srcp;
            if (region == 0) {
                int ar = m0 + row; ar = ar < N_NODES ? ar : N_NODES - 1;
                srcp = A + (size_t)ar * DIM + koff;
            } else {
                srcp = Bt + (size_t)(n0 + row) * DIM + koff;
            }
            unsigned short* lb = lds + region * 4096 + ((it & 1) * 256 + (tid & 192)) * 8;
            gl_lds16(srcp, lb);
        }
        asm volatile("s_waitcnt vmcnt(0)" ::: "memory");
        __syncthreads();

#pragma unroll
        for (int ks = 0; ks < 2; ks++) {
            bf16x8 ah[2], bh[2];
#pragma unroll
            for (int tm = 0; tm < 2; tm++) {
                int row = wm * 32 + tm * 16 + lr;
                int ph = (ks * 4 + kq) ^ (row & 7);
                ah[tm] = __builtin_bit_cast(bf16x8,
                    *reinterpret_cast<const short8*>(lds + row * 64 + ph * 8));
            }
#pragma unroll
            for (int tn = 0; tn < 2; tn++) {
                int col = wn * 32 + tn * 16 + lr;
                int ph = (ks * 4 + kq) ^ (col & 7);
                bh[tn] = __builtin_bit_cast(bf16x8,
                    *reinterpret_cast<const short8*>(lds + 4096 + col * 64 + ph * 8));
            }
#pragma unroll
            for (int tm = 0; tm < 2; tm++)
#pragma unroll
                for (int tn = 0; tn < 2; tn++)
                    acc[tm][tn] = MFMA(ah[tm], bh[tn], acc[tm][tn]);
        }
        if (t < 7) __syncthreads();
    }

#pragma unroll
    for (int tm = 0; tm < 2; tm++)
#pragma unroll
        for (int tn = 0; tn < 2; tn++) {
            int col = n0 + wn * 32 + tn * 16 + lr;
#pragma unroll
            for (int r4 = 0; r4 < 4; r4++) {
                int row = m0 + wm * 32 + tm * 16 + kq * 4 + r4;
                if (row < N_NODES) Hout[(size_t)row * DIM + col] = f32_to_bf16(acc[tm][tn][r4]);
            }
        }
}

// ---------------- lean gather: ONE wave per node, precomputed weights ----------------
// lane covers 8 cols at c0 = lane*8; head hd = lane>>4; w = wbuf[p*4+hd] (16B line broadcast).
#define ACC8(w_, hq)                                                        \
    {                                                                       \
        s += w_;                                                            \
        acc[0] += w_ * bits_f32((hq).x << 16);                              \
        acc[1] += w_ * bits_f32((hq).x & 0xFFFF0000u);                      \
        acc[2] += w_ * bits_f32((hq).y << 16);                              \
        acc[3] += w_ * bits_f32((hq).y & 0xFFFF0000u);                      \
        acc[4] += w_ * bits_f32((hq).z << 16);                              \
        acc[5] += w_ * bits_f32((hq).z & 0xFFFF0000u);                      \
        acc[6] += w_ * bits_f32((hq).w << 16);                              \
        acc[7] += w_ * bits_f32((hq).w & 0xFFFF0000u);                      \
    }

__global__ __launch_bounds__(256) void k_agg(const int* __restrict__ offsets,
                                             const int* __restrict__ csr_src,
                                             const float* __restrict__ wbuf,
                                             const unsigned short* __restrict__ H,
                                             const float* __restrict__ bias,
                                             const float* __restrict__ resid_f32,
                                             const unsigned short* __restrict__ resid_b16,
                                             float* __restrict__ out_f32,
                                             unsigned short* __restrict__ out_b16) {
    int v = (blockIdx.x * blockDim.x + threadIdx.x) >> 6;
    if (v >= N_NODES) return;
    int lane = threadIdx.x & 63;
    int c0 = lane * 8;
    int hd = lane >> 4;

    int beg = offsets[v], deg = offsets[v + 1] - beg;
    const int* cp = csr_src + beg;
    const float* wb = wbuf + (size_t)beg * 4 + hd;

    float acc[8] = {0.f, 0.f, 0.f, 0.f, 0.f, 0.f, 0.f, 0.f};
    float s = 0.f;
    int i = 0;
    for (; i + 8 <= deg; i += 8) {
        int u[8];
        float w[8];
#pragma unroll
        for (int j = 0; j < 8; j++) u[j] = cp[i + j];
#pragma unroll
        for (int j = 0; j < 8; j++) w[j] = wb[(size_t)(i + j) * 4];
        uint4 hq[8];
#pragma unroll
        for (int j = 0; j < 8; j++)
            hq[j] = *reinterpret_cast<const uint4*>(H + (size_t)u[j] * DIM + c0);
#pragma unroll
        for (int j = 0; j < 8; j++) ACC8(w[j], hq[j]);
    }
    for (; i < deg; i++) {
        int u0 = cp[i];
        float w0 = wb[(size_t)i * 4];
        uint4 h0 = *reinterpret_cast<const uint4*>(H + (size_t)u0 * DIM + c0);
        ACC8(w0, h0);
    }

    float inv = deg > 0 ? 1.0f / s : 0.f;
    const float4* bp = reinterpret_cast<const float4*>(bias + c0);
    float4 b0 = bp[0], b1 = bp[1];
    float bv[8] = {b0.x, b0.y, b0.z, b0.w, b1.x, b1.y, b1.z, b1.w};
    float o[8];
#pragma unroll
    for (int j = 0; j < 8; j++) {
        float t = acc[j] * inv + bv[j];
        o[j] = t > 0.f ? t : expm1f(t);
    }
    if (resid_f32) {
        const float4* rp = reinterpret_cast<const float4*>(resid_f32 + (size_t)v * DIM + c0);
        float4 r0 = rp[0], r1 = rp[1];
        o[0] += r0.x; o[1] += r0.y; o[2] += r0.z; o[3] += r0.w;
        o[4] += r1.x; o[5] += r1.y; o[6] += r1.z; o[7] += r1.w;
    } else {
        short8 rv = *reinterpret_cast<const short8*>(resid_b16 + (size_t)v * DIM + c0);
#pragma unroll
        for (int j = 0; j < 8; j++) o[j] += bf16_to_f32((unsigned short)rv[j]);
    }
    if (out_f32) {
        float4 w0 = {o[0], o[1], o[2], o[3]};
        float4 w1 = {o[4], o[5], o[6], o[7]};
        float4* op = reinterpret_cast<float4*>(out_f32 + (size_t)v * DIM + c0);
        op[0] = w0;
        op[1] = w1;
    }
    if (out_b16) {
        short8 ob;
#pragma unroll
        for (int j = 0; j < 8; j++) ob[j] = (short)f32_to_bf16(o[j]);
        *reinterpret_cast<short8*>(out_b16 + (size_t)v * DIM + c0) = ob;
    }
}

extern "C" void kernel_launch(void* const* d_in, const int* in_sizes, int n_in,
                              void* d_out, int out_size, void* d_ws, size_t ws_size,
                              hipStream_t stream) {
    const float* x = (const float*)d_in[0];
    const int* ei = (const int*)d_in[1];
    const int* src = ei;
    const int* dst = ei + N_EDGES;
    const float* W1 = (const float*)d_in[5];
    const float* a1 = (const float*)d_in[6];
    const float* b1 = (const float*)d_in[7];
    const float* W2 = (const float*)d_in[8];
    const float* a2 = (const float*)d_in[9];
    const float* b2 = (const float*)d_in[10];

    char* ws = (char*)d_ws;
    size_t off = 0;
    auto alloc = [&](size_t bytes) -> void* {
        void* p = ws + off;
        off += (bytes + 255) & ~(size_t)255;
        return p;
    };
    unsigned short* xb   = (unsigned short*)alloc((size_t)N_NODES * DIM * 2);  // x bf16, then x1 bf16
    unsigned short* h    = (unsigned short*)alloc((size_t)N_NODES * DIM * 2);
    float* als           = (float*)alloc((size_t)N_NODES * 8 * 4);  // als | ald contiguous
    float* ald           = als + (size_t)N_NODES * 4;
    unsigned short* B1   = (unsigned short*)alloc((size_t)DIM * DIM * 2);
    unsigned short* B2   = (unsigned short*)alloc((size_t)DIM * DIM * 2);
    float* wt1           = (float*)alloc((size_t)8 * DIM * 4);
    float* wt2           = (float*)alloc((size_t)8 * DIM * 4);
    int* offsets         = (int*)alloc((size_t)(N_NODES + 1) * 4);
    int* cursor          = (int*)alloc((size_t)N_NODES * 4);
    int* counts          = (int*)alloc((size_t)N_NODES * 4);
    int* csr_src         = (int*)alloc((size_t)N_EDGES * 4);
    int* csr_dst         = (int*)alloc((size_t)N_EDGES * 4);
    float* wbuf          = (float*)alloc((size_t)N_EDGES * 4 * 4);

    const int EB = (N_EDGES + 255) / 256;   // 1250

    // prologue: zero counts, then fused cast/transW/wtilde/hist
    hipMemsetAsync(counts, 0, (size_t)N_NODES * 4, stream);
    k_prep<<<5288 + EB, 256, 0, stream>>>(x, xb, W1, B1, W2, B2, a1, wt1, a2, wt2, dst, counts);
    k_scan<<<1, 1024, 0, stream>>>(counts, offsets, cursor);
    k_fill<<<EB, 256, 0, stream>>>(src, dst, cursor, csr_src, csr_dst);

    const int GEMM_BLOCKS = ((N_NODES + BM - 1) / BM) * (DIM / BN);  // 313 * 8 = 2504
    const int ALS_BLOCKS = (N_NODES + 3) / 4;                        // 5000
    const int AGG_BLOCKS = (N_NODES + 3) / 4;                        // 5000 (1 wave/node)

    // ---- layer 1 ----
    k_gemm_t<<<GEMM_BLOCKS, 256, 0, stream>>>(xb, B1, h);
    k_als<<<ALS_BLOCKS, 256, 0, stream>>>(xb, wt1, als, ald);
    k_edgew<<<EB, 256, 0, stream>>>(csr_src, csr_dst, als, ald, wbuf);
    // resid = x (f32); output bf16 x1 into xb (k_agg doesn't read xb)
    k_agg<<<AGG_BLOCKS, 256, 0, stream>>>(offsets, csr_src, wbuf, h, b1,
                                          x, nullptr, nullptr, xb);

    // ---- layer 2 ----
    k_gemm_t<<<GEMM_BLOCKS, 256, 0, stream>>>(xb, B2, h);
    k_als<<<ALS_BLOCKS, 256, 0, stream>>>(xb, wt2, als, ald);
    k_edgew<<<EB, 256, 0, stream>>>(csr_src, csr_dst, als, ald, wbuf);
    // resid = x1 (bf16); output f32 d_out
    k_agg<<<AGG_BLOCKS, 256, 0, stream>>>(offsets, csr_src, wbuf, h, b2,
                                          nullptr, xb, (float*)d_out, nullptr);
}

// Round 12
// 263.105 us; speedup vs baseline: 1.4073x; 1.0704x over previous
//
#include <hip/hip_runtime.h>
#include <hip/hip_bf16.h>
#include <math.h>

#define N_NODES 20000
#define N_EDGES 320000
#define DIM 512
#define HEADS 4
#define DHEAD 128
#define NEG_SLOPE 0.2f
#define BM 64
#define BN 64
#define BK 64
#define GEMM_BLOCKS 2504   // 313 * 8
#define ALS_BLOCKS 5000    // 4 nodes per block

typedef __attribute__((ext_vector_type(8))) short short8;
typedef __attribute__((ext_vector_type(8))) __bf16 bf16x8;
typedef __attribute__((ext_vector_type(4))) float f32x4;

static __device__ __forceinline__ unsigned short f32_to_bf16(float f) {
    union { float f; unsigned u; } v; v.f = f;
    unsigned u = v.u;
    u += 0x7FFFu + ((u >> 16) & 1u);   // round-to-nearest-even
    return (unsigned short)(u >> 16);
}
static __device__ __forceinline__ float bf16_to_f32(unsigned short s) {
    union { unsigned u; float f; } v; v.u = ((unsigned)s) << 16;
    return v.f;
}
static __device__ __forceinline__ float bits_f32(unsigned u) {
    union { unsigned u; float f; } v; v.u = u;
    return v.f;
}

static __device__ __forceinline__ void gl_lds16(const unsigned short* g, unsigned short* l) {
    __builtin_amdgcn_global_load_lds(
        (const __attribute__((address_space(1))) unsigned int*)g,
        (__attribute__((address_space(3))) unsigned int*)l, 16, 0, 0);
}

// ---------------- fused prologue: cast | transW x2 | wtilde x2 | hist ----------------
static __device__ __forceinline__ void do_cast(const float* in, unsigned short* out, int i) {
    const float4* p = reinterpret_cast<const float4*>(in) + (size_t)i * 2;
    float4 a = p[0], b = p[1];
    short8 o;
    o[0] = (short)f32_to_bf16(a.x); o[1] = (short)f32_to_bf16(a.y);
    o[2] = (short)f32_to_bf16(a.z); o[3] = (short)f32_to_bf16(a.w);
    o[4] = (short)f32_to_bf16(b.x); o[5] = (short)f32_to_bf16(b.y);
    o[6] = (short)f32_to_bf16(b.z); o[7] = (short)f32_to_bf16(b.w);
    *reinterpret_cast<short8*>(out + (size_t)i * 8) = o;
}
static __device__ __forceinline__ void do_transW(const float* W, unsigned short* Bt, int id) {
    int col = id >> 6;
    int kg = id & 63;
    int h = col >> 7;
    int f = col & 127;
    short8 o;
#pragma unroll
    for (int j = 0; j < 8; j++) {
        int k = kg * 8 + j;
        o[j] = (short)f32_to_bf16(W[(size_t)h * DIM * DHEAD + (size_t)k * DHEAD + f]);
    }
    *reinterpret_cast<short8*>(Bt + (size_t)col * DIM + kg * 8) = o;
}
static __device__ __forceinline__ void do_wtilde(const float* W, const float* a, float* wt, int id) {
    int v = id >> 9, k = id & 511;
    int h = v >> 1, sd = v & 1;
    const float* Wr = W + ((size_t)h * DIM + k) * DHEAD;
    const float* av = a + h * 2 * DHEAD + sd * DHEAD;
    float s = 0.f;
#pragma unroll 4
    for (int f = 0; f < DHEAD; f++) s += Wr[f] * av[f];
    wt[(size_t)v * DIM + k] = s;
}

__global__ void k_prep(const float* __restrict__ x, unsigned short* __restrict__ xb,
                       const float* __restrict__ W1, unsigned short* __restrict__ B1,
                       const float* __restrict__ W2, unsigned short* __restrict__ B2,
                       const float* __restrict__ a1, float* __restrict__ wt1,
                       const float* __restrict__ a2, float* __restrict__ wt2,
                       const int* __restrict__ dst, int* __restrict__ counts) {
    int b = blockIdx.x, tid = threadIdx.x;
    if (b < 5000) {
        do_cast(x, xb, b * 256 + tid);
    } else if (b < 5128) {
        do_transW(W1, B1, (b - 5000) * 256 + tid);
    } else if (b < 5256) {
        do_transW(W2, B2, (b - 5128) * 256 + tid);
    } else if (b < 5272) {
        do_wtilde(W1, a1, wt1, (b - 5256) * 256 + tid);
    } else if (b < 5288) {
        do_wtilde(W2, a2, wt2, (b - 5272) * 256 + tid);
    } else {
        int e = (b - 5288) * 256 + tid;
        if (e < N_EDGES) atomicAdd(&counts[dst[e]], 1);
    }
}

// ---------------- CSR build ----------------
__global__ void k_scan(const int* __restrict__ counts, int* __restrict__ offsets,
                       int* __restrict__ cursor) {
    __shared__ int lds[1024];
    int t = threadIdx.x;
    const int CH = (N_NODES + 1023) / 1024;   // 20
    int base = t * CH;
    int sum = 0;
    for (int j = 0; j < CH; j++) {
        int i = base + j;
        if (i < N_NODES) sum += counts[i];
    }
    lds[t] = sum;
    __syncthreads();
    for (int off = 1; off < 1024; off <<= 1) {
        int other = (t >= off) ? lds[t - off] : 0;
        __syncthreads();
        lds[t] += other;
        __syncthreads();
    }
    int excl = lds[t] - sum;
    int run = excl;
    for (int j = 0; j < CH; j++) {
        int i = base + j;
        if (i < N_NODES) {
            offsets[i] = run;
            cursor[i] = run;
            run += counts[i];
        }
    }
    if (t == 0) offsets[N_NODES] = N_EDGES;
}

__global__ void k_fill(const int* __restrict__ src, const int* __restrict__ dst,
                       int* __restrict__ cursor, int* __restrict__ csr_src) {
    int e = blockIdx.x * blockDim.x + threadIdx.x;
    if (e >= N_EDGES) return;
    int d = dst[e];
    int p = atomicAdd(&cursor[d], 1);
    csr_src[p] = src[e];
}

// ---------------- fused GEMM + attention logits (independent roles, shared 16KB LDS) ----------
// blocks [0, GEMM_BLOCKS): bf16 GEMM H[m][c] = sum_k A[m][k]*Bt[c][k]  (R7 structure)
// blocks [GEMM_BLOCKS, GEMM_BLOCKS+ALS_BLOCKS): als[n][h] = x[n,:]·wt[h*2], ald likewise
#define MFMA(a, b, c) __builtin_amdgcn_mfma_f32_16x16x32_bf16(a, b, c, 0, 0, 0)

__global__ __launch_bounds__(256, 8) void k_gemm_als(const unsigned short* __restrict__ A,
                                                     const unsigned short* __restrict__ Bt,
                                                     unsigned short* __restrict__ Hout,
                                                     const float* __restrict__ wt,
                                                     float* __restrict__ als,
                                                     float* __restrict__ ald) {
    __shared__ __align__(16) char sbuf[16384];
    const int tid = threadIdx.x;

    if (blockIdx.x < GEMM_BLOCKS) {
        unsigned short* lds = (unsigned short*)sbuf;
        // bijective XCD swizzle: 2504 = 8 * 313 exactly
        const int orig = blockIdx.x;
        const int wgid = (orig & 7) * 313 + (orig >> 3);
        const int mb = wgid >> 3, nb = wgid & 7;
        const int m0 = mb * BM, n0 = nb * BN;
        const int lane = tid & 63, wid = tid >> 6;
        const int wm = wid >> 1, wn = wid & 1;
        const int lr = lane & 15, kq = lane >> 4;

        f32x4 acc[2][2];
#pragma unroll
        for (int i = 0; i < 2; i++)
#pragma unroll
            for (int j = 0; j < 2; j++) acc[i][j] = (f32x4){0.f, 0.f, 0.f, 0.f};

#pragma unroll 1
        for (int t = 0; t < 8; t++) {
            const int k0 = t * BK;
#pragma unroll
            for (int it = 0; it < 4; it++) {
                const int region = it >> 1;              // 0=A 1=B
                int c = (it & 1) * 256 + tid;            // 0..511
                int row = c >> 3;                        // 0..63
                int sl = (c & 7) ^ (row & 7);            // inverse-swizzled source slot
                int koff = k0 + sl * 8;
                const unsigned short* srcp;
                if (region == 0) {
                    int ar = m0 + row; ar = ar < N_NODES ? ar : N_NODES - 1;
                    srcp = A + (size_t)ar * DIM + koff;
                } else {
                    srcp = Bt + (size_t)(n0 + row) * DIM + koff;
                }
                unsigned short* lb = lds + region * 4096 + ((it & 1) * 256 + (tid & 192)) * 8;
                gl_lds16(srcp, lb);
            }
            asm volatile("s_waitcnt vmcnt(0)" ::: "memory");
            __syncthreads();

#pragma unroll
            for (int ks = 0; ks < 2; ks++) {
                bf16x8 ah[2], bh[2];
#pragma unroll
                for (int tm = 0; tm < 2; tm++) {
                    int row = wm * 32 + tm * 16 + lr;
                    int ph = (ks * 4 + kq) ^ (row & 7);
                    ah[tm] = __builtin_bit_cast(bf16x8,
                        *reinterpret_cast<const short8*>(lds + row * 64 + ph * 8));
                }
#pragma unroll
                for (int tn = 0; tn < 2; tn++) {
                    int col = wn * 32 + tn * 16 + lr;
                    int ph = (ks * 4 + kq) ^ (col & 7);
                    bh[tn] = __builtin_bit_cast(bf16x8,
                        *reinterpret_cast<const short8*>(lds + 4096 + col * 64 + ph * 8));
                }
#pragma unroll
                for (int tm = 0; tm < 2; tm++)
#pragma unroll
                    for (int tn = 0; tn < 2; tn++)
                        acc[tm][tn] = MFMA(ah[tm], bh[tn], acc[tm][tn]);
            }
            if (t < 7) __syncthreads();
        }

#pragma unroll
        for (int tm = 0; tm < 2; tm++)
#pragma unroll
            for (int tn = 0; tn < 2; tn++) {
                int col = n0 + wn * 32 + tn * 16 + lr;
#pragma unroll
                for (int r4 = 0; r4 < 4; r4++) {
                    int row = m0 + wm * 32 + tm * 16 + kq * 4 + r4;
                    if (row < N_NODES) Hout[(size_t)row * DIM + col] = f32_to_bf16(acc[tm][tn][r4]);
                }
            }
    } else {
        // ---- als role ----
        float* wl = (float*)sbuf;   // 8*DIM floats = 16 KB
        for (int i = tid; i < 8 * DIM / 4; i += 256)
            reinterpret_cast<float4*>(wl)[i] = reinterpret_cast<const float4*>(wt)[i];
        __syncthreads();
        int n = (blockIdx.x - GEMM_BLOCKS) * 4 + (tid >> 6);
        if (n >= N_NODES) return;
        int lane = tid & 63;
        short8 xv8 = *reinterpret_cast<const short8*>(A + (size_t)n * DIM + lane * 8);
        float xv[8];
#pragma unroll
        for (int j = 0; j < 8; j++) xv[j] = bf16_to_f32((unsigned short)xv8[j]);
        float p[8] = {0.f, 0.f, 0.f, 0.f, 0.f, 0.f, 0.f, 0.f};
#pragma unroll
        for (int j = 0; j < 8; j++) {
            int k = lane * 8 + j;
#pragma unroll
            for (int v = 0; v < 8; v++) p[v] += xv[j] * wl[v * DIM + k];
        }
#pragma unroll
        for (int off = 1; off < 64; off <<= 1)
#pragma unroll
            for (int v = 0; v < 8; v++) p[v] += __shfl_xor(p[v], off);
        if (lane == 0) {
            float4 s = {p[0], p[2], p[4], p[6]};
            float4 d = {p[1], p[3], p[5], p[7]};
            *reinterpret_cast<float4*>(als + (size_t)n * 4) = s;
            *reinterpret_cast<float4*>(ald + (size_t)n * 4) = d;
        }
    }
}

// ---------------- single-pass aggregation with inline edge weights ----------------
// wave = node v; lane covers 8 cols at c0 = lane*8; head hd = lane>>4.
// w = exp(leaky(als[u][hd] + ald[v][hd])); alpha = w / sum(w). |logit| <= ~45 << 88: safe.
#define ACC8(w_, hq)                                                        \
    {                                                                       \
        s += w_;                                                            \
        acc[0] += w_ * bits_f32((hq).x << 16);                              \
        acc[1] += w_ * bits_f32((hq).x & 0xFFFF0000u);                      \
        acc[2] += w_ * bits_f32((hq).y << 16);                              \
        acc[3] += w_ * bits_f32((hq).y & 0xFFFF0000u);                      \
        acc[4] += w_ * bits_f32((hq).z << 16);                              \
        acc[5] += w_ * bits_f32((hq).z & 0xFFFF0000u);                      \
        acc[6] += w_ * bits_f32((hq).w << 16);                              \
        acc[7] += w_ * bits_f32((hq).w & 0xFFFF0000u);                      \
    }

__global__ __launch_bounds__(256) void k_agg(const int* __restrict__ offsets,
                                             const int* __restrict__ csr_src,
                                             const float* __restrict__ als,
                                             const float* __restrict__ ald,
                                             const unsigned short* __restrict__ H,
                                             const float* __restrict__ bias,
                                             const float* __restrict__ resid_f32,
                                             const unsigned short* __restrict__ resid_b16,
                                             float* __restrict__ out_f32,
                                             unsigned short* __restrict__ out_b16) {
    int v = (blockIdx.x * blockDim.x + threadIdx.x) >> 6;
    if (v >= N_NODES) return;
    int lane = threadIdx.x & 63;
    int c0 = lane * 8;
    int hd = lane >> 4;

    int beg = offsets[v], deg = offsets[v + 1] - beg;
    float aldh = ald[v * 4 + hd];
    const int* cp = csr_src + beg;

    float acc[8] = {0.f, 0.f, 0.f, 0.f, 0.f, 0.f, 0.f, 0.f};
    float s = 0.f;
    int i = 0;
    for (; i + 8 <= deg; i += 8) {
        int u[8];
#pragma unroll
        for (int j = 0; j < 8; j++) u[j] = cp[i + j];
        float e[8];
#pragma unroll
        for (int j = 0; j < 8; j++) e[j] = als[u[j] * 4 + hd];
        uint4 hq[8];
#pragma unroll
        for (int j = 0; j < 8; j++)
            hq[j] = *reinterpret_cast<const uint4*>(H + (size_t)u[j] * DIM + c0);
#pragma unroll
        for (int j = 0; j < 8; j++) {
            float sc = e[j] + aldh;
            sc = fmaxf(sc, NEG_SLOPE * sc);
            float w = __expf(sc);
            ACC8(w, hq[j]);
        }
    }
    for (; i < deg; i++) {
        int u0 = cp[i];
        float e0 = als[u0 * 4 + hd];
        uint4 h0 = *reinterpret_cast<const uint4*>(H + (size_t)u0 * DIM + c0);
        float sc = e0 + aldh;
        sc = fmaxf(sc, NEG_SLOPE * sc);
        float w = __expf(sc);
        ACC8(w, h0);
    }

    float inv = deg > 0 ? 1.0f / s : 0.f;
    const float4* bp = reinterpret_cast<const float4*>(bias + c0);
    float4 b0 = bp[0], b1 = bp[1];
    float bv[8] = {b0.x, b0.y, b0.z, b0.w, b1.x, b1.y, b1.z, b1.w};
    float o[8];
#pragma unroll
    for (int j = 0; j < 8; j++) {
        float t = acc[j] * inv + bv[j];
        o[j] = t > 0.f ? t : expm1f(t);
    }
    if (resid_f32) {
        const float4* rp = reinterpret_cast<const float4*>(resid_f32 + (size_t)v * DIM + c0);
        float4 r0 = rp[0], r1 = rp[1];
        o[0] += r0.x; o[1] += r0.y; o[2] += r0.z; o[3] += r0.w;
        o[4] += r1.x; o[5] += r1.y; o[6] += r1.z; o[7] += r1.w;
    } else {
        short8 rv = *reinterpret_cast<const short8*>(resid_b16 + (size_t)v * DIM + c0);
#pragma unroll
        for (int j = 0; j < 8; j++) o[j] += bf16_to_f32((unsigned short)rv[j]);
    }
    if (out_f32) {
        float4 w0 = {o[0], o[1], o[2], o[3]};
        float4 w1 = {o[4], o[5], o[6], o[7]};
        float4* op = reinterpret_cast<float4*>(out_f32 + (size_t)v * DIM + c0);
        op[0] = w0;
        op[1] = w1;
    }
    if (out_b16) {
        short8 ob;
#pragma unroll
        for (int j = 0; j < 8; j++) ob[j] = (short)f32_to_bf16(o[j]);
        *reinterpret_cast<short8*>(out_b16 + (size_t)v * DIM + c0) = ob;
    }
}

extern "C" void kernel_launch(void* const* d_in, const int* in_sizes, int n_in,
                              void* d_out, int out_size, void* d_ws, size_t ws_size,
                              hipStream_t stream) {
    const float* x = (const float*)d_in[0];
    const int* ei = (const int*)d_in[1];
    const int* src = ei;
    const int* dst = ei + N_EDGES;
    const float* W1 = (const float*)d_in[5];
    const float* a1 = (const float*)d_in[6];
    const float* b1 = (const float*)d_in[7];
    const float* W2 = (const float*)d_in[8];
    const float* a2 = (const float*)d_in[9];
    const float* b2 = (const float*)d_in[10];

    char* ws = (char*)d_ws;
    size_t off = 0;
    auto alloc = [&](size_t bytes) -> void* {
        void* p = ws + off;
        off += (bytes + 255) & ~(size_t)255;
        return p;
    };
    unsigned short* xb   = (unsigned short*)alloc((size_t)N_NODES * DIM * 2);  // x bf16, then x1 bf16
    unsigned short* h    = (unsigned short*)alloc((size_t)N_NODES * DIM * 2);
    float* als           = (float*)alloc((size_t)N_NODES * 8 * 4);  // als | ald contiguous
    float* ald           = als + (size_t)N_NODES * 4;
    unsigned short* B1   = (unsigned short*)alloc((size_t)DIM * DIM * 2);
    unsigned short* B2   = (unsigned short*)alloc((size_t)DIM * DIM * 2);
    float* wt1           = (float*)alloc((size_t)8 * DIM * 4);
    float* wt2           = (float*)alloc((size_t)8 * DIM * 4);
    int* offsets         = (int*)alloc((size_t)(N_NODES + 1) * 4);
    int* cursor          = (int*)alloc((size_t)N_NODES * 4);
    int* counts          = (int*)alloc((size_t)N_NODES * 4);
    int* csr_src         = (int*)alloc((size_t)N_EDGES * 4);

    const int EB = (N_EDGES + 255) / 256;   // 1250

    // prologue: zero counts, then fused cast/transW/wtilde/hist, scan, fill
    hipMemsetAsync(counts, 0, (size_t)N_NODES * 4, stream);
    k_prep<<<5288 + EB, 256, 0, stream>>>(x, xb, W1, B1, W2, B2, a1, wt1, a2, wt2, dst, counts);
    k_scan<<<1, 1024, 0, stream>>>(counts, offsets, cursor);
    k_fill<<<EB, 256, 0, stream>>>(src, dst, cursor, csr_src);

    const int FUSED_BLOCKS = GEMM_BLOCKS + ALS_BLOCKS;   // 7504
    const int AGG_BLOCKS = (N_NODES + 3) / 4;            // 5000 (1 wave/node)

    // ---- layer 1 ----
    k_gemm_als<<<FUSED_BLOCKS, 256, 0, stream>>>(xb, B1, h, wt1, als, ald);
    // resid = x (f32); output bf16 x1 into xb (k_agg doesn't read xb)
    k_agg<<<AGG_BLOCKS, 256, 0, stream>>>(offsets, csr_src, als, ald, h, b1,
                                          x, nullptr, nullptr, xb);

    // ---- layer 2 ----
    k_gemm_als<<<FUSED_BLOCKS, 256, 0, stream>>>(xb, B2, h, wt2, als, ald);
    // resid = x1 (bf16); output f32 d_out
    k_agg<<<AGG_BLOCKS, 256, 0, stream>>>(offsets, csr_src, als, ald, h, b2,
                                          nullptr, xb, (float*)d_out, nullptr);
}